// Round 5
// baseline (81.392 us; speedup 1.0000x reference)
//
#include <hip/hip_runtime.h>
#include <hip/hip_bf16.h>

typedef __attribute__((ext_vector_type(8))) short s16x8;
typedef __attribute__((ext_vector_type(4))) float f32x4;
typedef __attribute__((ext_vector_type(2))) unsigned int u32x2;
typedef __attribute__((ext_vector_type(4))) unsigned int u32x4;

#define MFMA16(a, b, c) __builtin_amdgcn_mfma_f32_16x16x32_bf16((a), (b), (c), 0, 0, 0)
#define LOG2E 1.4426950408889634f

static __device__ __forceinline__ unsigned int pk2(float a, float b) {
  union { __hip_bfloat162 h2; unsigned int u; } cv;
  cv.h2 = __float22bfloat162_rn(make_float2(a, b));
  return cv.u;
}
static __device__ __forceinline__ int div7(int x) { return (x * 9363) >> 16; }  // exact 0..62
static __device__ __forceinline__ int swz256(int row, int byteoff) {
  return row * 256 + (byteoff ^ ((row & 7) << 4));
}
static __device__ __forceinline__ int swz128(int row, int byteoff) {
  return row * 128 + (byteoff ^ ((row & 7) << 4));
}

// ---------- prep: weights fp32->bf16 ; rpbm[case][head][64][64] = (rpb + mask)*log2e ----------
__global__ void swin_prep(const float* __restrict__ wq, const float* __restrict__ wk,
                          const float* __restrict__ wv, const float* __restrict__ wp,
                          const float* __restrict__ rpb_table,
                          unsigned short* __restrict__ wsW, float* __restrict__ rpbm) {
  int idx = blockIdx.x * 256 + threadIdx.x;
  if (idx < 65536) {
    int t = idx >> 14, loc = idx & 16383;
    const float* s = (t == 0) ? wq : (t == 1) ? wk : (t == 2) ? wv : wp;
    union { __hip_bfloat16 h; unsigned short u; } cv;
    cv.h = __float2bfloat16(s[loc]);
    wsW[idx] = cv.u;
  } else {
    int k = idx - 65536;               // [case(2b)][head(2b)][i(6b)][j(6b)]
    int c = k >> 14;
    int h = (k >> 12) & 3;
    int i = (k >> 6) & 63, j = k & 63;
    float val;
    if (j >= 49) val = -1e30f;
    else if (i >= 49) val = 0.f;
    else {
      int yi = div7(i), xi = i - yi * 7;
      int yj = div7(j), xj = j - yj * 7;
      int ridx = (yi - yj + 6) * 13 + (xi - xj + 6);
      val = rpb_table[ridx * 4 + h];
      int cwi = c >> 1, cwj = c & 1;
      int rgi = (cwi ? (yi < 4 ? 3 : 6) : 0) + (cwj ? (xi < 4 ? 1 : 2) : 0);
      int rgj = (cwi ? (yj < 4 ? 3 : 6) : 0) + (cwj ? (xj < 4 ? 1 : 2) : 0);
      if (rgi != rgj) val -= 100.f;
      val *= LOG2E;
    }
    rpbm[k] = val;
  }
}

// ---------- main: one 512-thread WG per (batch, window) ----------
__global__ __launch_bounds__(512, 4) void swin_main(
    const float* __restrict__ xq, const float* __restrict__ xk, const float* __restrict__ xv,
    const float* __restrict__ bq, const float* __restrict__ bk, const float* __restrict__ bv,
    const float* __restrict__ bp, const unsigned short* __restrict__ wsW,
    const float* __restrict__ rpbm, float* __restrict__ out) {
  // R0 [0,16K): X then O ; R1 [16K,32K): Q then P(h=0,1)
  // R2 [32K,48K): K then P(h=2,3) ; R3 [48K,64K): V^T [128ch][64tok]
  __shared__ __align__(16) char sm[65536];

  const int tid = threadIdx.x;
  const int lane = tid & 63;
  const int wv_ = tid >> 6;       // wave 0..7
  const int l15 = lane & 15;
  const int lg = lane >> 4;       // 0..3
  const int kgrp = lg * 8;
  const int rsub = lg * 4;

  const int bid = blockIdx.x;
  const int b = bid >> 6;
  const int widx = bid & 63;
  const int wi = widx >> 3, wj = widx & 7;
  const long obase = (long)b * 56 * 56 * 128;
  const int mcase = ((wi == 7) ? 2 : 0) + ((wj == 7) ? 1 : 0);

  // ---- X prefetch: thread owns (row = tid>>3, 16 ch) ----
  const int xrow = tid >> 3;
  const int xk16 = (tid & 7) << 4;
  long xoff = -1;
  if (xrow < 49) {
    int ty = div7(xrow), tx = xrow - ty * 7;
    int ih = wi * 7 + ty + 3; if (ih >= 56) ih -= 56;
    int iw = wj * 7 + tx + 3; if (iw >= 56) iw -= 56;
    xoff = obase + (long)((ih * 56 + iw) * 128 + xk16);
  }
  float xr[16];
#pragma unroll
  for (int i = 0; i < 16; ++i) xr[i] = 0.f;

  auto issue_x = [&](const float* src) {
    if (xoff >= 0) {
      const float* p = src + xoff;
#pragma unroll
      for (int q = 0; q < 4; ++q) {
        f32x4 v = *(const f32x4*)(p + q * 4);
        xr[q * 4 + 0] = v[0]; xr[q * 4 + 1] = v[1];
        xr[q * 4 + 2] = v[2]; xr[q * 4 + 3] = v[3];
      }
    }
  };
  auto write_x = [&]() {
    unsigned int w[8];
#pragma unroll
    for (int i = 0; i < 8; ++i) w[i] = pk2(xr[2 * i], xr[2 * i + 1]);
    u32x4 a = {w[0], w[1], w[2], w[3]};
    u32x4 bb = {w[4], w[5], w[6], w[7]};
    *(u32x4*)(sm + swz256(xrow, xk16 * 2)) = a;
    *(u32x4*)(sm + swz256(xrow, xk16 * 2 + 16)) = bb;
  };
  auto st2 = [&](int a0, int a1, float v0, float v1) {
    unsigned int u = pk2(v0, v1);
    *(unsigned short*)(sm + a0) = (unsigned short)u;
    *(unsigned short*)(sm + a1) = (unsigned short)(u >> 16);
  };

  // ---- linearT: D[n][tok] = mfma(A=W, B=X) -> row-major dst via b64 writes ----
  // wave w owns out-channels [16w, 16w+16); lane holds 4 consecutive ch of one token.
  auto linearT = [&](int woff, const float* bias, float scale, int dstbase) {
    const int nrow = wv_ * 16 + l15;
    s16x8 afr[4];
#pragma unroll
    for (int kt = 0; kt < 4; ++kt)
      afr[kt] = *(const s16x8*)(wsW + woff + nrow * 128 + kt * 32 + kgrp);
    f32x4 bv4 = *(const f32x4*)(bias + wv_ * 16 + rsub);
    float bb0 = bv4[0] * scale, bb1 = bv4[1] * scale;
    float bb2 = bv4[2] * scale, bb3 = bv4[3] * scale;
#pragma unroll
    for (int tt = 0; tt < 4; ++tt) {
      f32x4 acc = {0.f, 0.f, 0.f, 0.f};
#pragma unroll
      for (int kt = 0; kt < 4; ++kt) {
        s16x8 bfr = *(const s16x8*)(sm + swz256(tt * 16 + l15, (kt * 32 + kgrp) * 2));
        acc = MFMA16(afr[kt], bfr, acc);
      }
      u32x2 pkw = {pk2(acc[0] * scale + bb0, acc[1] * scale + bb1),
                   pk2(acc[2] * scale + bb2, acc[3] * scale + bb3)};
      *(u32x2*)(sm + dstbase + swz256(tt * 16 + l15, 2 * (wv_ * 16 + rsub))) = pkw;
    }
  };

  // ---- linearV: D[tok][n] = mfma(A=X, B=W) -> V^T [ch][tok] via b64 writes ----
  auto linearV = [&](int woff, const float* bias) {
    const int n = wv_ * 16 + l15;
    s16x8 bfr[4];
#pragma unroll
    for (int kt = 0; kt < 4; ++kt)
      bfr[kt] = *(const s16x8*)(wsW + woff + n * 128 + kt * 32 + kgrp);
    float bval = bias[n];
#pragma unroll
    for (int mt = 0; mt < 4; ++mt) {
      f32x4 acc = {0.f, 0.f, 0.f, 0.f};
#pragma unroll
      for (int kt = 0; kt < 4; ++kt) {
        s16x8 afr = *(const s16x8*)(sm + swz256(mt * 16 + l15, (kt * 32 + kgrp) * 2));
        acc = MFMA16(afr, bfr[kt], acc);
      }
      u32x2 pkw = {pk2(acc[0] + bval, acc[1] + bval), pk2(acc[2] + bval, acc[3] + bval)};
      *(u32x2*)(sm + 49152 + swz128(n, 2 * (mt * 16 + rsub))) = pkw;
    }
  };

  const float QSCALE = 0.17677669529663687f * LOG2E;  // 32^-0.5 * log2(e)

  issue_x(xq);
  write_x(); __syncthreads();                         // B1: Xq
  issue_x(xk);
  linearT(0, bq, QSCALE, 16384); __syncthreads();     // B2: Q done
  write_x(); __syncthreads();                         // B3: Xk
  issue_x(xv);
  linearT(16384, bk, 1.f, 32768); __syncthreads();    // B4: K done
  write_x(); __syncthreads();                         // B5: Xv

  // ---- fused phase: V-linear + QK^T + softmax (no barrier inside) ----
  const int h = wv_ & 3;
  const int half = wv_ >> 2;
  const int coff = h * 32;
  f32x4 S[2][4];
  {
    linearV(32768, bv);                               // V^T -> R3 (reads Xv in R0)

    // rpbm loads (L2-hot), issued before QK^T MFMAs
    const float* rpbm_h = rpbm + (((mcase << 2) + h) << 12);
    float rv[2][4][4];
#pragma unroll
    for (int m2 = 0; m2 < 2; ++m2)
#pragma unroll
      for (int r = 0; r < 4; ++r) {
        int i = (half * 2 + m2) * 16 + rsub + r;
        const float* rp = rpbm_h + i * 64 + l15;
#pragma unroll
        for (int jt = 0; jt < 4; ++jt) rv[m2][jt][r] = rp[jt * 16];
      }

    s16x8 kfr[4];
#pragma unroll
    for (int jt = 0; jt < 4; ++jt)
      kfr[jt] = *(const s16x8*)(sm + 32768 + swz256(jt * 16 + l15, (coff + kgrp) * 2));
#pragma unroll
    for (int m2 = 0; m2 < 2; ++m2) {
      int mt = half * 2 + m2;
      s16x8 qfr = *(const s16x8*)(sm + 16384 + swz256(mt * 16 + l15, (coff + kgrp) * 2));
#pragma unroll
      for (int jt = 0; jt < 4; ++jt) {
        f32x4 z = {0.f, 0.f, 0.f, 0.f};
        S[m2][jt] = MFMA16(qfr, kfr[jt], z);
      }
    }

    // S += rpbm (bias+mask+pad, pre-scaled by log2e)
#pragma unroll
    for (int m2 = 0; m2 < 2; ++m2)
#pragma unroll
      for (int jt = 0; jt < 4; ++jt)
#pragma unroll
        for (int r = 0; r < 4; ++r) S[m2][jt][r] += rv[m2][jt][r];

    // row softmax (base-2)
#pragma unroll
    for (int m2 = 0; m2 < 2; ++m2) {
#pragma unroll
      for (int r = 0; r < 4; ++r) {
        float m = fmaxf(fmaxf(S[m2][0][r], S[m2][1][r]), fmaxf(S[m2][2][r], S[m2][3][r]));
        for (int d = 1; d < 16; d <<= 1) m = fmaxf(m, __shfl_xor(m, d));
        float e0 = exp2f(S[m2][0][r] - m);
        float e1 = exp2f(S[m2][1][r] - m);
        float e2 = exp2f(S[m2][2][r] - m);
        float e3 = exp2f(S[m2][3][r] - m);
        float s = e0 + e1 + e2 + e3;
        for (int d = 1; d < 16; d <<= 1) s += __shfl_xor(s, d);
        float inv = 1.0f / s;
        S[m2][0][r] = e0 * inv; S[m2][1][r] = e1 * inv;
        S[m2][2][r] = e2 * inv; S[m2][3][r] = e3 * inv;
      }
    }
  }
  __syncthreads();   // B6: V^T complete; all Q/K + Xv reads done

  const int pbase = 16384 + h * 8192;  // P[64][64] bf16 per head
#pragma unroll
  for (int m2 = 0; m2 < 2; ++m2) {
    int i0 = (half * 2 + m2) * 16 + rsub;
#pragma unroll
    for (int jt = 0; jt < 4; ++jt) {
      int bo = 2 * (jt * 16 + l15);
      st2(pbase + swz128(i0, bo), pbase + swz128(i0 + 1, bo), S[m2][jt][0], S[m2][jt][1]);
      st2(pbase + swz128(i0 + 2, bo), pbase + swz128(i0 + 3, bo), S[m2][jt][2], S[m2][jt][3]);
    }
  }
  __syncthreads();   // B7: P visible

  {
    // PV : O[q][ch] via D = mfma(A=V^T, B=P) -> lane = q-token, rows = ch
    s16x8 vfr[2][2];
#pragma unroll
    for (int ks = 0; ks < 2; ++ks)
#pragma unroll
      for (int ct = 0; ct < 2; ++ct) {
        int c = coff + ct * 16 + l15;
        vfr[ks][ct] = *(const s16x8*)(sm + 49152 + swz128(c, (ks * 32 + kgrp) * 2));
      }
    f32x4 Oacc[2][2];   // [ct][qt]
#pragma unroll
    for (int ct = 0; ct < 2; ++ct)
#pragma unroll
      for (int qt = 0; qt < 2; ++qt) Oacc[ct][qt] = (f32x4){0.f, 0.f, 0.f, 0.f};
#pragma unroll
    for (int qt = 0; qt < 2; ++qt) {
#pragma unroll
      for (int ks = 0; ks < 2; ++ks) {
        s16x8 pfr = *(const s16x8*)(sm + pbase + swz128((half * 2 + qt) * 16 + l15, (ks * 32 + kgrp) * 2));
        Oacc[0][qt] = MFMA16(vfr[ks][0], pfr, Oacc[0][qt]);
        Oacc[1][qt] = MFMA16(vfr[ks][1], pfr, Oacc[1][qt]);
      }
    }
    // O row-major [tok][ch] into R0 via b64 writes
#pragma unroll
    for (int ct = 0; ct < 2; ++ct)
#pragma unroll
      for (int qt = 0; qt < 2; ++qt) {
        int qtok = (half * 2 + qt) * 16 + l15;
        u32x2 pkw = {pk2(Oacc[ct][qt][0], Oacc[ct][qt][1]),
                     pk2(Oacc[ct][qt][2], Oacc[ct][qt][3])};
        *(u32x2*)(sm + swz256(qtok, 2 * (coff + ct * 16 + rsub))) = pkw;
      }
  }
  __syncthreads();   // B8: O visible

  // ---- proj: D[n][tok] = mfma(A=Wp, B=O) -> dwordx4 rolled stores ----
  {
    const int nrow = wv_ * 16 + l15;
    s16x8 afr[4];
#pragma unroll
    for (int kt = 0; kt < 4; ++kt)
      afr[kt] = *(const s16x8*)(wsW + 49152 + nrow * 128 + kt * 32 + kgrp);
    f32x4 bv4 = *(const f32x4*)(bp + wv_ * 16 + rsub);
#pragma unroll
    for (int tt = 0; tt < 4; ++tt) {
      f32x4 acc = {0.f, 0.f, 0.f, 0.f};
#pragma unroll
      for (int kt = 0; kt < 4; ++kt) {
        s16x8 bfr = *(const s16x8*)(sm + swz256(tt * 16 + l15, (kt * 32 + kgrp) * 2));
        acc = MFMA16(afr[kt], bfr, acc);
      }
      int tok = tt * 16 + l15;
      if (tok < 49) {
        int ty = div7(tok), tx = tok - ty * 7;
        int oh = wi * 7 + ty + 3; if (oh >= 56) oh -= 56;
        int ow = wj * 7 + tx + 3; if (ow >= 56) ow -= 56;
        f32x4 res = {acc[0] + bv4[0], acc[1] + bv4[1], acc[2] + bv4[2], acc[3] + bv4[3]};
        *(f32x4*)(out + obase + (oh * 56 + ow) * 128 + wv_ * 16 + rsub) = res;
      }
    }
  }
}

extern "C" void kernel_launch(void* const* d_in, const int* in_sizes, int n_in,
                              void* d_out, int out_size, void* d_ws, size_t ws_size,
                              hipStream_t stream) {
  const float* xq = (const float*)d_in[0];
  const float* xk = (const float*)d_in[1];
  const float* xv = (const float*)d_in[2];
  const float* wq = (const float*)d_in[3];
  const float* bq = (const float*)d_in[4];
  const float* wk = (const float*)d_in[5];
  const float* bk = (const float*)d_in[6];
  const float* wv = (const float*)d_in[7];
  const float* bv = (const float*)d_in[8];
  const float* wp = (const float*)d_in[9];
  const float* bp = (const float*)d_in[10];
  const float* rpb = (const float*)d_in[11];

  unsigned short* wsW = (unsigned short*)d_ws;          // 4 x 16384 bf16 = 128 KB
  float* rpbm = (float*)((char*)d_ws + 131072);         // 4*4*64*64 f32 = 256 KB

  swin_prep<<<512, 256, 0, stream>>>(wq, wk, wv, wp, rpb, wsW, rpbm);

  float* out = (float*)d_out;
  swin_main<<<2048, 512, 0, stream>>>(xq, xk, xv, bq, bk, bv, bp, wsW, rpbm, out);
}